// Round 10
// baseline (121.164 us; speedup 1.0000x reference)
//
#include <hip/hip_runtime.h>
#include <stdint.h>

// MedianFilter (f32 in / f32 out), round 10: R9 + VGPR budget fix (the only change that
// the counters actually motivate: VGPR_Count=32 while P3 has >=45 live words => compiler
// was re-reading operands from LDS; occupancy is LDS-capped at 8 blocks/CU so 64 VGPRs
// are free -> __launch_bounds__(256, 8) + short-live-range P3 ordering).
//   out0 = normalize(clip(unnormalize(median7x7_reflect(image))))
//   out1 = mask (copy), fused (gridDim.z slices 24..31)
//
// Block: 64x16 px, 256 threads. Thread (q,ty): pixels cols 2q,2q+1, rows 2ty,2ty+1
// (vertical pair packed in u16x2 lanes).
//   P1: stage 22x70 halo keys transposed -> keyT[col][row] (interior fast path).
//   P2: sort 560 packed columns (21 CE) -> scol[y0][parity][col/2][e], x-major lanes.
//   P3: middle cols 2q+1..2q+6: pairs 3x25 CE, quad merge(14,14) 64 CE, cone-pruned
//       merge(28,14) -> union ranks 17..24 (53 CE); THEN load side cols; per pixel
//       median-of-15 via sel15 (14 CE).  ~266 CE/thread for 4 px.
// Exactness: monotone bf16-key map commutes with the median order statistic; the
// median-of-49 has >=17 of the 6-col middle below and above => it is the median of
// M[17..24] U sidecol (15 elems). Epilogue replays numpy f32 ops (no FMA).
// absmax floor 0.001953125 (bf16-key quantization, threshold 0.0223).

#define TW 64
#define TH 16
#define LW (TW + 6)    // 70 cols incl. halo
#define LHK 22         // key rows incl. halo
#define LHP 26         // keyT row capacity: 52 B stride (13 banks, odd), 4B-aligned
#define HW 512

typedef unsigned short u16x2 __attribute__((ext_vector_type(2)));

__device__ __forceinline__ void ce(uint32_t &a, uint32_t &b) {
  u16x2 av = __builtin_bit_cast(u16x2, a);
  u16x2 bv = __builtin_bit_cast(u16x2, b);
  u16x2 lo = __builtin_elementwise_min(av, bv);   // v_pk_min_u16
  u16x2 hi = __builtin_elementwise_max(av, bv);   // v_pk_max_u16
  a = __builtin_bit_cast(uint32_t, lo);
  b = __builtin_bit_cast(uint32_t, hi);
}

template<int L, int P>
__device__ __forceinline__ void bitonic_merge(uint32_t *buf) {
#pragma unroll
  for (int s = L >> 1; s >= 1; s >>= 1) {
#pragma unroll
    for (int i = 0; i < L; ++i) {
      if (((i & s) == 0) && i >= P)
        ce(buf[i], buf[i + s]);
    }
  }
}

template<int M, int N>
__device__ __forceinline__ void merge2(const uint32_t *a, const uint32_t *b, uint32_t *out) {
  constexpr int T = M + N;
  constexpr int L = (T <= 2) ? 2 : (T <= 4) ? 4 : (T <= 8) ? 8 : (T <= 16) ? 16 : (T <= 32) ? 32 : 64;
  constexpr int P = L - T;
  uint32_t buf[L];
#pragma unroll
  for (int i = 0; i < M; ++i) buf[P + i] = a[i];
#pragma unroll
  for (int i = 0; i < N; ++i) buf[P + M + i] = b[N - 1 - i];
  bitonic_merge<L, P>(buf);
#pragma unroll
  for (int i = 0; i < T; ++i) out[i] = buf[P + i];
}

// median of 15 from sorted A[8] (asc) and sorted B[7] (asc): 14 CE.
__device__ __forceinline__ uint32_t sel15(const uint32_t *A, const uint32_t *B) {
  uint32_t t[16];
#pragma unroll
  for (int i = 0; i < 8; ++i) t[1 + i] = A[i];
#pragma unroll
  for (int i = 0; i < 7; ++i) t[9 + i] = B[6 - i];
#pragma unroll
  for (int i = 1; i < 8; ++i) ce(t[i], t[i + 8]);   // s=8 (i=0 pad no-op)
  ce(t[8], t[12]); ce(t[9], t[13]); ce(t[10], t[14]); ce(t[11], t[15]);  // s=4
  ce(t[8], t[10]); ce(t[9], t[11]);                                      // s=2
  ce(t[8], t[9]);                                                        // s=1
  return t[8];
}

__device__ __forceinline__ uint32_t f32_key(float f) {
  union { float f; uint32_t u; } cv; cv.f = f;
  uint32_t u = cv.u;
  uint32_t h = (u + 0x7FFFu + ((u >> 16) & 1u)) >> 16;
  h &= 0xFFFFu;
  return (h & 0x8000u) ? (~h & 0xFFFFu) : (h | 0x8000u);
}

__device__ __forceinline__ float key_to_f32(uint32_t k) {
  uint32_t h = (k & 0x8000u) ? (k ^ 0x8000u) : (~k & 0xFFFFu);
  union { uint32_t u; float f; } cv; cv.u = h << 16;
  return cv.f;
}

__global__ __launch_bounds__(256, 8) void fused_kernel(
    const float* __restrict__ img, const float* __restrict__ mask,
    float* __restrict__ out) {
  // ---- fused mask copy: z slices 24..31 ----
  if (blockIdx.z >= 24) {
    int flat = (((int)(blockIdx.z - 24) * gridDim.y + blockIdx.y) * gridDim.x + blockIdx.x) * 256
               + threadIdx.x;
    const float4* s = (const float4*)mask;
    float4* d = (float4*)(out + (size_t)8 * 3 * HW * HW);
    d[flat] = s[flat];
    return;
  }

  __shared__ uint16_t keyT[LW][LHP];              // 70x26 u16 = 3640 B
  __shared__ uint32_t scol[8][2][LW / 2][7];      // parity-split sorted cols: 15680 B

  const int q  = threadIdx.x & 31;                // pixel-pair column group: cols 2q, 2q+1
  const int ty = threadIdx.x >> 5;                // pair-row: pixel rows 2ty, 2ty+1
  const int bx = blockIdx.x * TW;
  const int by = blockIdx.y * TH;
  const int z  = blockIdx.z;
  const size_t base = (size_t)z * (HW * HW);
  const float* src = img + base;

  // ---- P1: stage halo keys, transposed; interior fast path (block-uniform) ----
  const bool interior = (bx != 0) && (bx != HW - TW) && (by != 0) && (by != HW - TH);
  if (interior) {
    const float* p0 = src + (size_t)(by - 3) * HW + (bx - 3);
    for (int idx = threadIdx.x; idx < LHK * LW; idx += 256) {
      int r = idx / LW, cc = idx - r * LW;
      keyT[cc][r] = (uint16_t)f32_key(p0[r * HW + cc]);
    }
  } else {
    for (int idx = threadIdx.x; idx < LHK * LW; idx += 256) {
      int r = idx / LW, cc = idx - r * LW;
      int gy = by - 3 + r;
      int gx = bx - 3 + cc;
      gy = (gy < 0) ? -gy : ((gy >= HW) ? (2 * HW - 2 - gy) : gy);
      gx = (gx < 0) ? -gx : ((gx >= HW) ? (2 * HW - 2 - gx) : gx);
      keyT[cc][r] = (uint16_t)f32_key(src[gy * HW + gx]);
    }
  }
  __syncthreads();

  // ---- P2: sort 560 packed columns, x-major lane mapping ----
  for (int cidx = threadIdx.x; cidx < 8 * LW; cidx += 256) {
    int y0 = cidx / LW, x = cidx - y0 * LW;
    const uint32_t* colp = (const uint32_t*)&keyT[x][2 * y0];  // 4B-aligned
    uint32_t w0 = colp[0], w1 = colp[1], w2 = colp[2], w3 = colp[3];
    uint32_t col[7];
    col[0] = w0; col[2] = w1; col[4] = w2; col[6] = w3;
    col[1] = __builtin_amdgcn_alignbit(w1, w0, 16);
    col[3] = __builtin_amdgcn_alignbit(w2, w1, 16);
    col[5] = __builtin_amdgcn_alignbit(w3, w2, 16);
#pragma unroll
    for (int a = 1; a < 7; ++a)
#pragma unroll
      for (int b = a; b > 0; --b)
        ce(col[b - 1], col[b]);
#pragma unroll
    for (int e = 0; e < 7; ++e)
      scol[y0][x & 1][x >> 1][e] = col[e];
  }
  __syncthreads();

  // ---- P3: middle columns first (cols 2q+1..2q+6), side columns late ----
  // col 2q+i lives at scol[ty][i&1][q + (i>>1)][e]
  uint32_t pa[14], pb[14], pc[14];
  {
    uint32_t ca[7], cb[7];
#pragma unroll
    for (int e = 0; e < 7; ++e) { ca[e] = scol[ty][1][q][e];     cb[e] = scol[ty][0][q + 1][e]; }
    merge2<7, 7>(ca, cb, pa);                      // cols 2q+1, 2q+2
#pragma unroll
    for (int e = 0; e < 7; ++e) { ca[e] = scol[ty][1][q + 1][e]; cb[e] = scol[ty][0][q + 2][e]; }
    merge2<7, 7>(ca, cb, pb);                      // cols 2q+3, 2q+4
#pragma unroll
    for (int e = 0; e < 7; ++e) { ca[e] = scol[ty][1][q + 2][e]; cb[e] = scol[ty][0][q + 3][e]; }
    merge2<7, 7>(ca, cb, pc);                      // cols 2q+5, 2q+6
  }
  uint32_t Q[28];
  merge2<14, 14>(pa, pb, Q);                       // cols 2q+1..2q+4

  // ---- cone-pruned bitonic merge(Q[28], pc[14]) -> union ranks 17..24 ----
  // L=64, P=22; buf[22..49]=Q asc, buf[50..63]=pc desc; targets abs 39..46.
  uint32_t buf[64];
#pragma unroll
  for (int i = 0; i < 28; ++i) buf[22 + i] = Q[i];
#pragma unroll
  for (int i = 0; i < 14; ++i) buf[50 + i] = pc[13 - i];
#pragma unroll
  for (int i = 22; i < 32; ++i) ce(buf[i], buf[i + 32]);  // s=32
#pragma unroll
  for (int i = 32; i < 48; ++i) ce(buf[i], buf[i + 16]);  // s=16
#pragma unroll
  for (int i = 32; i < 40; ++i) ce(buf[i], buf[i + 8]);   // s=8
#pragma unroll
  for (int i = 32; i < 36; ++i) ce(buf[i], buf[i + 4]);   // s=4 lower
#pragma unroll
  for (int i = 40; i < 44; ++i) ce(buf[i], buf[i + 4]);   // s=4 upper
  ce(buf[36], buf[38]); ce(buf[37], buf[39]);             // s=2
  ce(buf[40], buf[42]); ce(buf[41], buf[43]);
  ce(buf[44], buf[46]); ce(buf[45], buf[47]);
  ce(buf[38], buf[39]);                                   // s=1
  ce(buf[40], buf[41]); ce(buf[42], buf[43]);
  ce(buf[44], buf[45]); ce(buf[46], buf[47]);
  uint32_t mid8[8];                                       // M[17..24]
#pragma unroll
  for (int i = 0; i < 8; ++i) mid8[i] = buf[39 + i];

  // ---- side columns (loaded late: short live range) + per-pixel median-of-15 ----
  uint32_t d0[7], d7[7];
#pragma unroll
  for (int e = 0; e < 7; ++e) { d0[e] = scol[ty][0][q][e]; d7[e] = scol[ty][1][q + 3][e]; }
  uint32_t medA = sel15(mid8, d0);                 // pixel col 2q
  uint32_t medB = sel15(mid8, d7);                 // pixel col 2q+1

  // ---- epilogue: exact numpy f32 arithmetic (no FMA), coalesced float2 stores ----
  const int ch = z - (z / 3) * 3;
  float mean, stdv;
  if (ch == 0)      { mean = 0.485f; stdv = 0.229f; }
  else if (ch == 1) { mean = 0.456f; stdv = 0.224f; }
  else              { mean = 0.406f; stdv = 0.225f; }

#pragma unroll
  for (int p = 0; p < 2; ++p) {                    // p: row offset (lo/hi u16 lane)
    uint32_t ka = (p == 0) ? (medA & 0xFFFFu) : (medA >> 16);
    uint32_t kb = (p == 0) ? (medB & 0xFFFFu) : (medB >> 16);
    float ya = __fadd_rn(__fmul_rn(key_to_f32(ka), stdv), mean);
    ya = fminf(fmaxf(ya, 0.0f), 1.0f);
    ya = __fdiv_rn(__fsub_rn(ya, mean), stdv);
    float yb = __fadd_rn(__fmul_rn(key_to_f32(kb), stdv), mean);
    yb = fminf(fmaxf(yb, 0.0f), 1.0f);
    yb = __fdiv_rn(__fsub_rn(yb, mean), stdv);
    float2 v = {ya, yb};
    *(float2*)(out + base + (size_t)(by + 2 * ty + p) * HW + (bx + 2 * q)) = v;
  }
}

extern "C" void kernel_launch(void* const* d_in, const int* in_sizes, int n_in,
                              void* d_out, int out_size, void* d_ws, size_t ws_size,
                              hipStream_t stream) {
  const float* img  = (const float*)d_in[0];   // f32 [8,3,512,512]
  const float* mask = (const float*)d_in[1];   // f32 [8,1,512,512]
  float* out = (float*)d_out;                  // f32: out0 (6291456) ++ out1 (2097152)

  // z 0..23: image slices (8x32 blocks of 64x16 px); z 24..31: mask copy.
  dim3 grid(HW / TW, HW / TH, 24 + 8);
  fused_kernel<<<grid, 256, 0, stream>>>(img, mask, out);
}

// Round 11
// 111.764 us; speedup vs baseline: 1.0841x; 1.0841x over previous
//
#include <hip/hip_runtime.h>
#include <stdint.h>

// MedianFilter (f32 in / f32 out) — FINAL (revert to round-8 best: dur 112.0 µs).
//   out0 = normalize(clip(unnormalize(median7x7_reflect(image))))
//   out1 = mask (copy), fused (gridDim.z slices 24..31)
//
// R9 (conflict tweaks, interior fast path): neutral. R10 (launch_bounds(256,8) +
// P3 restructure): REGRESSED — WRITE_SIZE 32768->81920 KB revealed scratch spilling.
// R8 is the measured optimum of this structure.
//
// Block: 64x16 px, 256 threads. Thread (q,ty): pixels at cols 2q,2q+1, rows 2ty,2ty+1
// (vertical pair packed in u16x2 lanes).
//   P1: stage 22x70 halo keys transposed -> keyT[col][row]
//   P2: sort 560 packed columns (21 CE) -> scol[y0][parity][col/2][e]
//   P3: read 8 sorted cols; pairs (2q+1,2q+2),(2q+3,2q+4),(2q+5,2q+6): 3x25 CE;
//       quad merge(14,14): 64 CE; cone-pruned merge(28,14) -> union ranks 17..24: 53 CE;
//       per pixel: median-of-15 via sel15: 14 CE each.  ~266 CE/thread for 4 px.
// Exactness: monotone bf16-key map commutes with the median order statistic; the
// median-of-49 has >=17 of the 6-col middle below and above => it is the median of
// M[17..24] U sidecol (15 elems). Epilogue replays numpy f32 ops (no FMA).
// absmax floor 0.001953125 (bf16-key quantization; threshold 0.0223).

#define TW 64
#define TH 16
#define LW (TW + 6)    // 70 cols incl. halo
#define LHK 22         // key rows incl. halo
#define LHP 26         // keyT row capacity: 52 B stride (13 banks, odd), 4B-aligned
#define HW 512

typedef unsigned short u16x2 __attribute__((ext_vector_type(2)));

__device__ __forceinline__ void ce(uint32_t &a, uint32_t &b) {
  u16x2 av = __builtin_bit_cast(u16x2, a);
  u16x2 bv = __builtin_bit_cast(u16x2, b);
  u16x2 lo = __builtin_elementwise_min(av, bv);   // v_pk_min_u16
  u16x2 hi = __builtin_elementwise_max(av, bv);   // v_pk_max_u16
  a = __builtin_bit_cast(uint32_t, lo);
  b = __builtin_bit_cast(uint32_t, hi);
}

template<int L, int P>
__device__ __forceinline__ void bitonic_merge(uint32_t *buf) {
#pragma unroll
  for (int s = L >> 1; s >= 1; s >>= 1) {
#pragma unroll
    for (int i = 0; i < L; ++i) {
      if (((i & s) == 0) && i >= P)
        ce(buf[i], buf[i + s]);
    }
  }
}

template<int M, int N>
__device__ __forceinline__ void merge2(const uint32_t *a, const uint32_t *b, uint32_t *out) {
  constexpr int T = M + N;
  constexpr int L = (T <= 2) ? 2 : (T <= 4) ? 4 : (T <= 8) ? 8 : (T <= 16) ? 16 : (T <= 32) ? 32 : 64;
  constexpr int P = L - T;
  uint32_t buf[L];
#pragma unroll
  for (int i = 0; i < M; ++i) buf[P + i] = a[i];
#pragma unroll
  for (int i = 0; i < N; ++i) buf[P + M + i] = b[N - 1 - i];
  bitonic_merge<L, P>(buf);
#pragma unroll
  for (int i = 0; i < T; ++i) out[i] = buf[P + i];
}

// median of 15 from sorted A[8] (asc) and sorted B[7] (asc): 14 CE.
// Layout [pad, A asc, B desc] (L=16, P=1), target abs pos 8 = rank 7 of 15.
__device__ __forceinline__ uint32_t sel15(const uint32_t *A, const uint32_t *B) {
  uint32_t t[16];
#pragma unroll
  for (int i = 0; i < 8; ++i) t[1 + i] = A[i];
#pragma unroll
  for (int i = 0; i < 7; ++i) t[9 + i] = B[6 - i];
#pragma unroll
  for (int i = 1; i < 8; ++i) ce(t[i], t[i + 8]);   // s=8 (i=0 is pad no-op)
  ce(t[8], t[12]); ce(t[9], t[13]); ce(t[10], t[14]); ce(t[11], t[15]);  // s=4
  ce(t[8], t[10]); ce(t[9], t[11]);                                      // s=2
  ce(t[8], t[9]);                                                        // s=1
  return t[8];
}

// f32 -> bf16(RNE) bits -> sortable u16 key
__device__ __forceinline__ uint32_t f32_key(float f) {
  union { float f; uint32_t u; } cv; cv.f = f;
  uint32_t u = cv.u;
  uint32_t h = (u + 0x7FFFu + ((u >> 16) & 1u)) >> 16;
  h &= 0xFFFFu;
  return (h & 0x8000u) ? (~h & 0xFFFFu) : (h | 0x8000u);
}

__device__ __forceinline__ float key_to_f32(uint32_t k) {
  uint32_t h = (k & 0x8000u) ? (k ^ 0x8000u) : (~k & 0xFFFFu);
  union { uint32_t u; float f; } cv; cv.u = h << 16;
  return cv.f;
}

__global__ __launch_bounds__(256) void fused_kernel(
    const float* __restrict__ img, const float* __restrict__ mask,
    float* __restrict__ out) {
  // ---- fused mask copy: z slices 24..31 (8 * 8 * 32 * 256 * float4 = 2,097,152 f32) ----
  if (blockIdx.z >= 24) {
    int flat = (((int)(blockIdx.z - 24) * gridDim.y + blockIdx.y) * gridDim.x + blockIdx.x) * 256
               + threadIdx.x;
    const float4* s = (const float4*)mask;
    float4* d = (float4*)(out + (size_t)8 * 3 * HW * HW);
    d[flat] = s[flat];
    return;
  }

  __shared__ uint16_t keyT[LW][LHP];              // 70x26 u16 = 3640 B
  __shared__ uint32_t scol[8][2][LW / 2][7];      // parity-split sorted cols: 15680 B

  const int q  = threadIdx.x & 31;                // pixel-pair column group: cols 2q, 2q+1
  const int ty = threadIdx.x >> 5;                // pair-row: pixel rows 2ty, 2ty+1
  const int bx = blockIdx.x * TW;
  const int by = blockIdx.y * TH;
  const int z  = blockIdx.z;
  const size_t base = (size_t)z * (HW * HW);
  const float* src = img + base;

  // ---- P1: stage halo keys, transposed (reflect pad) ----
  for (int idx = threadIdx.x; idx < LHK * LW; idx += 256) {
    int r = idx / LW, cc = idx - r * LW;
    int gy = by - 3 + r;
    int gx = bx - 3 + cc;
    gy = (gy < 0) ? -gy : ((gy >= HW) ? (2 * HW - 2 - gy) : gy);
    gx = (gx < 0) ? -gx : ((gx >= HW) ? (2 * HW - 2 - gx) : gx);
    keyT[cc][r] = (uint16_t)f32_key(src[gy * HW + gx]);
  }
  __syncthreads();

  // ---- P2: sort 560 packed columns (8 bases x 70 cols), 21 CE each ----
  for (int cidx = threadIdx.x; cidx < 8 * LW; cidx += 256) {
    int y0 = cidx & 7, x = cidx >> 3;
    const uint32_t* colp = (const uint32_t*)&keyT[x][2 * y0];  // 4B-aligned
    uint32_t w0 = colp[0], w1 = colp[1], w2 = colp[2], w3 = colp[3];
    uint32_t col[7];
    col[0] = w0; col[2] = w1; col[4] = w2; col[6] = w3;
    col[1] = __builtin_amdgcn_alignbit(w1, w0, 16);
    col[3] = __builtin_amdgcn_alignbit(w2, w1, 16);
    col[5] = __builtin_amdgcn_alignbit(w3, w2, 16);
#pragma unroll
    for (int a = 1; a < 7; ++a)
#pragma unroll
      for (int b = a; b > 0; --b)
        ce(col[b - 1], col[b]);
#pragma unroll
    for (int e = 0; e < 7; ++e)
      scol[y0][x & 1][x >> 1][e] = col[e];
  }
  __syncthreads();

  // ---- P3: read 8 sorted cols (2q .. 2q+7) ----
  uint32_t s_[8][7];
#pragma unroll
  for (int i = 0; i < 8; ++i) {
    int par = i & 1;                               // col 2q+i: parity = i&1, half = q + i/2
    int hf  = q + (i >> 1);
#pragma unroll
    for (int e = 0; e < 7; ++e)
      s_[i][e] = scol[ty][par][hf][e];
  }

  // pairs of the shared middle (cols 2q+1..2q+6)
  uint32_t pa[14], pb[14], pc[14];
  merge2<7, 7>(s_[1], s_[2], pa);
  merge2<7, 7>(s_[3], s_[4], pb);
  merge2<7, 7>(s_[5], s_[6], pc);
  uint32_t Q[28];
  merge2<14, 14>(pa, pb, Q);                       // cols 2q+1..2q+4

  // ---- cone-pruned bitonic merge(Q[28], pc[14]) -> only union ranks 17..24 ----
  // Layout: L=64, P=22; buf[22..49]=Q asc, buf[50..63]=pc desc; targets abs 39..46.
  uint32_t buf[64];
#pragma unroll
  for (int i = 0; i < 28; ++i) buf[22 + i] = Q[i];
#pragma unroll
  for (int i = 0; i < 14; ++i) buf[50 + i] = pc[13 - i];
#pragma unroll
  for (int i = 22; i < 32; ++i) ce(buf[i], buf[i + 32]);  // s=32: 10 CE (i<22 pads)
#pragma unroll
  for (int i = 32; i < 48; ++i) ce(buf[i], buf[i + 16]);  // s=16: [32,48)<->[48,64)
#pragma unroll
  for (int i = 32; i < 40; ++i) ce(buf[i], buf[i + 8]);   // s=8
#pragma unroll
  for (int i = 32; i < 36; ++i) ce(buf[i], buf[i + 4]);   // s=4 lower
#pragma unroll
  for (int i = 40; i < 44; ++i) ce(buf[i], buf[i + 4]);   // s=4 upper
  ce(buf[36], buf[38]); ce(buf[37], buf[39]);             // s=2
  ce(buf[40], buf[42]); ce(buf[41], buf[43]);
  ce(buf[44], buf[46]); ce(buf[45], buf[47]);
  ce(buf[38], buf[39]);                                   // s=1
  ce(buf[40], buf[41]); ce(buf[42], buf[43]);
  ce(buf[44], buf[45]); ce(buf[46], buf[47]);
  uint32_t mid8[8];                                       // M[17..24]
#pragma unroll
  for (int i = 0; i < 8; ++i) mid8[i] = buf[39 + i];

  // ---- per-pixel selection: median of 15 ----
  uint32_t medA = sel15(mid8, s_[0]);              // pixel col 2q   (rows 2ty, 2ty+1)
  uint32_t medB = sel15(mid8, s_[7]);              // pixel col 2q+1

  // ---- epilogue: exact numpy f32 arithmetic (no FMA), coalesced float2 stores ----
  const int ch = z - (z / 3) * 3;
  float mean, stdv;
  if (ch == 0)      { mean = 0.485f; stdv = 0.229f; }
  else if (ch == 1) { mean = 0.456f; stdv = 0.224f; }
  else              { mean = 0.406f; stdv = 0.225f; }

#pragma unroll
  for (int p = 0; p < 2; ++p) {                    // p: row offset (lo/hi u16 lane)
    uint32_t ka = (p == 0) ? (medA & 0xFFFFu) : (medA >> 16);
    uint32_t kb = (p == 0) ? (medB & 0xFFFFu) : (medB >> 16);
    float ya = __fadd_rn(__fmul_rn(key_to_f32(ka), stdv), mean);
    ya = fminf(fmaxf(ya, 0.0f), 1.0f);
    ya = __fdiv_rn(__fsub_rn(ya, mean), stdv);
    float yb = __fadd_rn(__fmul_rn(key_to_f32(kb), stdv), mean);
    yb = fminf(fmaxf(yb, 0.0f), 1.0f);
    yb = __fdiv_rn(__fsub_rn(yb, mean), stdv);
    float2 v = {ya, yb};
    *(float2*)(out + base + (size_t)(by + 2 * ty + p) * HW + (bx + 2 * q)) = v;
  }
}

extern "C" void kernel_launch(void* const* d_in, const int* in_sizes, int n_in,
                              void* d_out, int out_size, void* d_ws, size_t ws_size,
                              hipStream_t stream) {
  const float* img  = (const float*)d_in[0];   // f32 [8,3,512,512]
  const float* mask = (const float*)d_in[1];   // f32 [8,1,512,512]
  float* out = (float*)d_out;                  // f32: out0 (6291456) ++ out1 (2097152)

  // z 0..23: image slices (8x32 blocks of 64x16 px); z 24..31: mask copy.
  dim3 grid(HW / TW, HW / TH, 24 + 8);
  fused_kernel<<<grid, 256, 0, stream>>>(img, mask, out);
}